// Round 15
// baseline (3310.778 us; speedup 1.0000x reference)
//
#include <hip/hip_runtime.h>
#include <cstdint>

// ---------------------------------------------------------------------------
// WindowAttention: pad 96->100, roll(+2,+2), 4x4 windows, MHA(8 heads,d=64),
// un-window, roll back, crop. Token m = g*10000 + hh*100 + ww (hh-major).
// Pipeline: gather -> qkv GEMM (256^2 SINGLE-buffer, 2 blocks/CU) -> attn
// -> out GEMM (same structure, LDS-assembled full-line NCHW scatter).
// ---------------------------------------------------------------------------

typedef __attribute__((ext_vector_type(8))) __bf16 bf16x8;
typedef __attribute__((ext_vector_type(8))) uint16_t u16x8;
typedef __attribute__((ext_vector_type(4))) float f32x4;

__device__ __forceinline__ uint16_t f2bf(float f) {
  union { float f; uint32_t u; } c; c.f = f;
  uint32_t r = c.u + 0x7FFFu + ((c.u >> 16) & 1u);  // RNE
  return (uint16_t)(r >> 16);
}
__device__ __forceinline__ float bf2f(uint16_t u) {
  union { uint32_t u; float f; } c; c.u = ((uint32_t)u) << 16;
  return c.f;
}

__device__ __forceinline__ void g2lds16(const void* g, void* lds) {
  __builtin_amdgcn_global_load_lds(
      (const __attribute__((address_space(1))) uint32_t*)(uintptr_t)g,
      (__attribute__((address_space(3))) uint32_t*)(uintptr_t)lds,
      16, 0, 0);
}

#define CFENCE asm volatile("" ::: "memory")
#define BAR do { CFENCE; __builtin_amdgcn_s_barrier(); CFENCE; } while (0)

// ---------------------------------------------------------------------------
__global__ void cvt_weights(const float* __restrict__ w1, const float* __restrict__ w2,
                            uint16_t* __restrict__ o1, uint16_t* __restrict__ o2) {
  int i = blockIdx.x * 256 + threadIdx.x;
  if (i < 786432) o1[i] = f2bf(w1[i]);
  if (i < 262144) o2[i] = f2bf(w2[i]);
}

// ---------------------------------------------------------------------------
// Gather: x (NCHW fp32) -> token-major bf16 X[m,512]; pad+roll folded in.
// ---------------------------------------------------------------------------
__global__ __launch_bounds__(256) void gather_kernel(
    const float* __restrict__ x, uint16_t* __restrict__ xbf, int n0) {
  __shared__ float tile[64][65];
  const int z = blockIdx.z;
  const int g = z / 100, hh = z % 100;
  const int c0 = blockIdx.y * 64, ww0 = blockIdx.x * 64;
  const int n = n0 + g;
  const int hp = (hh >= 2) ? hh - 2 : hh + 98;
  const bool hok = hp < 96;
  const int t = threadIdx.x;
  const int lane = t & 63, grp = t >> 6;

  const int ww = ww0 + lane;
  const int wp = (ww >= 2) ? ww - 2 : ww + 98;
  const bool wok = hok && (ww < 100) && (wp < 96);
  const float* xb = x + ((size_t)n * 512) * 9216 + (size_t)hp * 96 + wp;
#pragma unroll
  for (int i = 0; i < 16; ++i) {
    int c = grp + i * 4;
    tile[c][lane] = wok ? xb[(size_t)(c0 + c) * 9216] : 0.f;
  }
  __syncthreads();
#pragma unroll
  for (int i = 0; i < 16; ++i) {
    int wl = grp + i * 4;
    int www = ww0 + wl;
    if (www < 100) {
      int m = g * 10000 + hh * 100 + www;
      xbf[(size_t)m * 512 + c0 + lane] = f2bf(tile[lane][wl]);
    }
  }
}

// ---------------------------------------------------------------------------
// Single-buffered 256x256 GEMM, BK=64, K=512, 512 thr (8 waves 2Mx4N),
// LDS 69632B (staging A 32KB | B 32KB; EPI1 union [256][68] fp32) ->
// 2 blocks/CU: one block's stage-drain overlaps the other's compute.
// Per K-tile: STAGE -> vmcnt(0)+BAR -> {read a0,b; MFMA lo-half;
// read a1; MFMA hi-half} -> BAR. XOR-swizzle pair (byte ^= (row&7)<<4)
// via pre-swizzled global source + swizzled ds_read (verified 0-conflict).
// D[row,col] = sum_k A[row,k]*B[col,k]; both row-major, stride 512.
// EPI 0: qkv epilogue (bf16 scalar, +bias[col])  [R9-proven].
// EPI 1: out scatter: LDS-assembled ww-contiguous float4 runs [R9-proven].
// ---------------------------------------------------------------------------
template <int EPI, int NB, int MODE>
__global__ __launch_bounds__(512, 4) void gemmSB(
    const uint16_t* __restrict__ A, const uint16_t* __restrict__ B,
    const float* __restrict__ bias, uint16_t* __restrict__ Cbf,
    float* __restrict__ Cout, int Mg, int n0) {
  __shared__ alignas(16) uint16_t lds[34816];  // 69632 B
  const int t = threadIdx.x;
  const int w = t >> 6, lane = t & 63;
  const int wr = w >> 2, wc = w & 3;
  const int lr = lane & 15, lg = lane >> 4;

  // bijective XCD swizzle (m204)
  const int nwg = gridDim.x, bid = blockIdx.x;
  const int q = nwg >> 3, r = nwg & 7;
  const int xc = bid & 7, li = bid >> 3;
  const int wg = (xc < r ? xc * (q + 1) : r * (q + 1) + (xc - r) * q) + li;
  int bm, bn;
  if (MODE == 0) { bm = wg / NB; bn = wg % NB; }
  else           { bm = wg % NB; bn = wg / NB; }

  // stage one full K-tile: A[256][64] + B[256][64], 4096 16B-chunks, 8/thread
  auto STAGE = [&](int kt) {
#pragma unroll
    for (int i = 0; i < 4; ++i) {
      int e = i * 512 + t;                 // 0..2047
      int row = e >> 3, slot = e & 7;
      int kb = (slot ^ (row & 7)) << 3;    // pre-swizzled source column
      g2lds16(A + (size_t)(bm * 256 + row) * 512 + kt * 64 + kb,
              &lds[(size_t)e * 8]);
      g2lds16(B + (size_t)(bn * 256 + row) * 512 + kt * 64 + kb,
              &lds[16384 + (size_t)e * 8]);
    }
  };
  auto LDA = [&](int mi, int k2) -> bf16x8 {
    int row = wr * 128 + mi * 16 + lr;
    int byte = row * 128 + ((k2 * 64 + lg * 16) ^ ((row & 7) << 4));
    return *(const bf16x8*)((const char*)lds + byte);
  };
  auto LDB = [&](int ni, int k2) -> bf16x8 {
    int row = wc * 64 + ni * 16 + lr;
    int byte = 32768 + row * 128 + ((k2 * 64 + lg * 16) ^ ((row & 7) << 4));
    return *(const bf16x8*)((const char*)lds + byte);
  };

  f32x4 acc[8][4];
#pragma unroll
  for (int mi = 0; mi < 8; ++mi)
#pragma unroll
    for (int ni = 0; ni < 4; ++ni) acc[mi][ni] = (f32x4){0.f, 0.f, 0.f, 0.f};

  for (int kt = 0; kt < 8; ++kt) {
    STAGE(kt);
    asm volatile("s_waitcnt vmcnt(0)" ::: "memory");
    BAR;
    bf16x8 b[4][2];
#pragma unroll
    for (int ni = 0; ni < 4; ++ni)
#pragma unroll
      for (int k2 = 0; k2 < 2; ++k2) b[ni][k2] = LDB(ni, k2);
    {
      bf16x8 a0[4][2];
#pragma unroll
      for (int mi = 0; mi < 4; ++mi)
#pragma unroll
        for (int k2 = 0; k2 < 2; ++k2) a0[mi][k2] = LDA(mi, k2);
      __builtin_amdgcn_s_setprio(1);
#pragma unroll
      for (int mi = 0; mi < 4; ++mi)
#pragma unroll
        for (int ni = 0; ni < 4; ++ni)
#pragma unroll
          for (int k2 = 0; k2 < 2; ++k2)
            acc[mi][ni] = __builtin_amdgcn_mfma_f32_16x16x32_bf16(
                a0[mi][k2], b[ni][k2], acc[mi][ni], 0, 0, 0);
      __builtin_amdgcn_s_setprio(0);
    }
    {
      bf16x8 a1[4][2];
#pragma unroll
      for (int mi = 0; mi < 4; ++mi)
#pragma unroll
        for (int k2 = 0; k2 < 2; ++k2) a1[mi][k2] = LDA(mi + 4, k2);
      __builtin_amdgcn_s_setprio(1);
#pragma unroll
      for (int mi = 0; mi < 4; ++mi)
#pragma unroll
        for (int ni = 0; ni < 4; ++ni)
#pragma unroll
          for (int k2 = 0; k2 < 2; ++k2)
            acc[mi + 4][ni] = __builtin_amdgcn_mfma_f32_16x16x32_bf16(
                a1[mi][k2], b[ni][k2], acc[mi + 4][ni], 0, 0, 0);
      __builtin_amdgcn_s_setprio(0);
    }
    BAR;                                   // all waves done reading this tile
  }

  if (EPI == 0) {
#pragma unroll
    for (int ni = 0; ni < 4; ++ni) {
      int col = bn * 256 + wc * 64 + ni * 16 + lr;
      float bb = bias[col];
#pragma unroll
      for (int mi = 0; mi < 8; ++mi) {
        int row = bm * 256 + wr * 128 + mi * 16 + lg * 4;
#pragma unroll
        for (int rr = 0; rr < 4; ++rr)
          Cbf[(size_t)(row + rr) * 1536 + col] = f2bf(acc[mi][ni][rr] + bb);
      }
    }
  } else {
    // acc: c_local = wr*128 + mi*16 + lg*4 + rr ; tok = bn*256 + wc*64 + ni*16 + lr
    __syncthreads();
    float* ldsF = (float*)lds;  // [256][68] fp32 = 69632B
#pragma unroll
    for (int p = 0; p < 4; ++p) {
      if (wc == p) {
#pragma unroll
        for (int mi = 0; mi < 8; ++mi) {
          const float* b4 = &bias[bm * 256 + wr * 128 + mi * 16 + lg * 4];
#pragma unroll
          for (int ni = 0; ni < 4; ++ni)
#pragma unroll
            for (int rr = 0; rr < 4; ++rr)
              ldsF[(wr * 128 + mi * 16 + lg * 4 + rr) * 68 + ni * 16 + lr] =
                  acc[mi][ni][rr] + b4[rr];
        }
      }
      __syncthreads();
      // emit: 256 channels x 16 token-quads (64 tokens of pass p);
      // hh-major tokens => quad = 4 consecutive ww (ww % 4 == 0).
#pragma unroll
      for (int i = 0; i < 8; ++i) {
        int e = i * 512 + t;                  // 4096 chunks
        int q4 = e & 15, c = e >> 4;
        int tok = bn * 256 + p * 64 + q4 * 4;
        int g = tok / 10000, rem = tok - g * 10000;
        int hh = rem / 100, ww = rem - hh * 100;
        if (hh >= 2 && hh < 98) {
          float4 v = *(const float4*)&ldsF[c * 68 + q4 * 4];
          size_t base = ((size_t)(n0 + g) * 512 + bm * 256 + c) * 9216 +
                        (size_t)(hh - 2) * 96;
          if (ww >= 4 && ww <= 92) {
            *(float4*)&Cout[base + ww - 2] = v;          // full quad
          } else if (ww == 0) {
            Cout[base + 0] = v.z; Cout[base + 1] = v.w;  // ww=2,3
          } else if (ww == 96) {
            Cout[base + 94] = v.x; Cout[base + 95] = v.y; // ww=96,97
          }
        }
      }
      __syncthreads();
    }
  }
}

// ---------------------------------------------------------------------------
// Attention: 1 block/window, 128 thr = (head h, query qi). K/V staged in LDS,
// Q read direct. fp32 VALU softmax.  [R9-proven]
// ---------------------------------------------------------------------------
__global__ __launch_bounds__(128) void attn_kernel(
    const uint16_t* __restrict__ qkv, const float* __restrict__ x,
    uint16_t* __restrict__ obuf, int n0) {
  __shared__ alignas(16) uint16_t skv[16][1024];  // [row][K(512) V(512)]
  __shared__ float smask[16];
  const int b = blockIdx.x;
  const int g = b / 625, wid = b % 625;
  const int ib = wid / 25, jb = wid % 25;
  const int t = threadIdx.x;
  const int wv = t >> 6;
  const int h = t >> 4, qi = t & 15;

  const int mbase = g * 10000 + ib * 400 + jb * 4;  // hh-major token rows

#pragma unroll
  for (int it = 0; it < 16; ++it) {
    int e = it * 128 + t;                 // 16B chunk id in [0,2048)
    int l = e >> 7, c = e & 127;
    int m = mbase + (l >> 2) * 100 + (l & 3);
    const uint16_t* src = qkv + (size_t)m * 1536 + 512 + c * 8;
    g2lds16(src, (uint16_t*)skv + (it * 128 + wv * 64) * 8);
  }
  const int mq = mbase + (qi >> 2) * 100 + (qi & 3);
  float qv[64];
#pragma unroll
  for (int d8 = 0; d8 < 8; ++d8) {
    u16x8 v = *(const u16x8*)&qkv[(size_t)mq * 1536 + h * 64 + d8 * 8];
#pragma unroll
    for (int j = 0; j < 8; ++j) qv[d8 * 8 + j] = bf2f(v[j]);
  }
  if (t < 16) {
    int hh = ib * 4 + (t >> 2), ww = jb * 4 + (t & 3);
    int a = (hh >= 4) ? hh - 4 : hh + 96;
    int c = (ww >= 4) ? ww - 4 : ww + 96;
    smask[t] = (a < 96 && c < 96)
                   ? x[((size_t)(n0 + g) * 512) * 9216 + (size_t)a * 96 + c]
                   : 0.f;
  }
  __syncthreads();

  float s[16];
  float mx = -1e30f;
#pragma unroll
  for (int ki = 0; ki < 16; ++ki) {
    float a = 0.f;
#pragma unroll
    for (int d8 = 0; d8 < 8; ++d8) {
      u16x8 kv = *(const u16x8*)&skv[ki][h * 64 + d8 * 8];
#pragma unroll
      for (int j = 0; j < 8; ++j) a += qv[d8 * 8 + j] * bf2f(kv[j]);
    }
    s[ki] = a * 0.125f + smask[ki];
    mx = fmaxf(mx, s[ki]);
  }
  float sum = 0.f;
#pragma unroll
  for (int ki = 0; ki < 16; ++ki) { s[ki] = __expf(s[ki] - mx); sum += s[ki]; }
  const float inv = 1.f / sum;
  float o[64];
#pragma unroll
  for (int d = 0; d < 64; ++d) o[d] = 0.f;
#pragma unroll
  for (int ki = 0; ki < 16; ++ki) {
    float wgt = s[ki] * inv;
#pragma unroll
    for (int d8 = 0; d8 < 8; ++d8) {
      u16x8 vv = *(const u16x8*)&skv[ki][512 + h * 64 + d8 * 8];
#pragma unroll
      for (int j = 0; j < 8; ++j) o[d8 * 8 + j] += wgt * bf2f(vv[j]);
    }
  }
#pragma unroll
  for (int d8 = 0; d8 < 8; ++d8) {
    alignas(16) uint16_t tmp[8];
#pragma unroll
    for (int j = 0; j < 8; ++j) tmp[j] = f2bf(o[d8 * 8 + j]);
    *(uint4*)&obuf[(size_t)mq * 512 + h * 64 + d8 * 8] = *(uint4*)tmp;
  }
}

// ---------------------------------------------------------------------------
extern "C" void kernel_launch(void* const* d_in, const int* in_sizes, int n_in,
                              void* d_out, int out_size, void* d_ws, size_t ws_size,
                              hipStream_t stream) {
  const float* x  = (const float*)d_in[0];
  const float* wq = (const float*)d_in[1];
  const float* bq = (const float*)d_in[2];
  const float* wo = (const float*)d_in[3];
  const float* bo = (const float*)d_in[4];
  float* out = (float*)d_out;
  uint8_t* ws = (uint8_t*)d_ws;

  uint16_t* wq_bf = (uint16_t*)ws;               // 1.5 MB
  uint16_t* wo_bf = (uint16_t*)(ws + 1572864);   // 0.5 MB
  uint8_t* bufbase = ws + 2097152;

  const int Mg = 160000;                          // 16 * 10000, /256 = 625
  uint16_t* xo   = (uint16_t*)bufbase;                          // Mg*512 (X, then O)
  uint16_t* qkvb = (uint16_t*)(bufbase + (size_t)Mg * 1024);    // Mg*1536
  (void)ws_size;

  cvt_weights<<<dim3(3072), dim3(256), 0, stream>>>(wq, wo, wq_bf, wo_bf);

  gather_kernel<<<dim3(2, 8, 1600), dim3(256), 0, stream>>>(x, xo, 0);
  // qkv[m,1536] = X @ Wqkv^T + b  (625 m-tiles x 6 n-tiles)
  gemmSB<0, 6, 0><<<dim3(625 * 6), dim3(512), 0, stream>>>(
      xo, wq_bf, bq, qkvb, nullptr, Mg, 0);
  attn_kernel<<<dim3(10000), dim3(128), 0, stream>>>(qkvb, x, xo, 0);
  // out[c,tok] = Wout @ O^T + b, scattered to (N,C,96,96)  (2 x 625)
  gemmSB<1, 2, 1><<<dim3(625 * 2), dim3(512), 0, stream>>>(
      wo_bf, xo, bo, nullptr, out, Mg, 0);

  (void)in_sizes; (void)n_in; (void)out_size;
}

// Round 16
// 973.522 us; speedup vs baseline: 3.4008x; 3.4008x over previous
//
#include <hip/hip_runtime.h>
#include <cstdint>

// ---------------------------------------------------------------------------
// WindowAttention: pad 96->100, roll(+2,+2), 4x4 windows, MHA(8 heads,d=64),
// un-window, roll back, crop. Token m = g*10000 + hh*100 + ww (hh-major).
// Pipeline: gather -> qkv GEMM (256^2 8-phase) -> window attn -> out GEMM
// (transposed, LDS-assembled full-line NCHW scatter epilogue).
// FINAL: R9 build (best measured: 974us). All structural variants tried in
// R1-R15 regressed; the two real wins (hh-major order enabling coalesced
// scatter, LDS-assembled full-line EPI1) are included here.
// ---------------------------------------------------------------------------

typedef __attribute__((ext_vector_type(8))) __bf16 bf16x8;
typedef __attribute__((ext_vector_type(8))) uint16_t u16x8;
typedef __attribute__((ext_vector_type(4))) float f32x4;

__device__ __forceinline__ uint16_t f2bf(float f) {
  union { float f; uint32_t u; } c; c.f = f;
  uint32_t r = c.u + 0x7FFFu + ((c.u >> 16) & 1u);  // RNE
  return (uint16_t)(r >> 16);
}
__device__ __forceinline__ float bf2f(uint16_t u) {
  union { uint32_t u; float f; } c; c.u = ((uint32_t)u) << 16;
  return c.f;
}

__device__ __forceinline__ void g2lds16(const void* g, void* lds) {
  __builtin_amdgcn_global_load_lds(
      (const __attribute__((address_space(1))) uint32_t*)(uintptr_t)g,
      (__attribute__((address_space(3))) uint32_t*)(uintptr_t)lds,
      16, 0, 0);
}

#define CFENCE asm volatile("" ::: "memory")
#define BAR do { CFENCE; __builtin_amdgcn_s_barrier(); CFENCE; } while (0)
#define SCHED0 __builtin_amdgcn_sched_barrier(0)

// ---------------------------------------------------------------------------
__global__ void cvt_weights(const float* __restrict__ w1, const float* __restrict__ w2,
                            uint16_t* __restrict__ o1, uint16_t* __restrict__ o2) {
  int i = blockIdx.x * 256 + threadIdx.x;
  if (i < 786432) o1[i] = f2bf(w1[i]);
  if (i < 262144) o2[i] = f2bf(w2[i]);
}

// ---------------------------------------------------------------------------
// Gather: x (NCHW fp32) -> token-major bf16 X[m,512]; pad+roll folded in.
// ---------------------------------------------------------------------------
__global__ __launch_bounds__(256) void gather_kernel(
    const float* __restrict__ x, uint16_t* __restrict__ xbf, int n0) {
  __shared__ float tile[64][65];
  const int z = blockIdx.z;
  const int g = z / 100, hh = z % 100;
  const int c0 = blockIdx.y * 64, ww0 = blockIdx.x * 64;
  const int n = n0 + g;
  const int hp = (hh >= 2) ? hh - 2 : hh + 98;
  const bool hok = hp < 96;
  const int t = threadIdx.x;
  const int lane = t & 63, grp = t >> 6;

  const int ww = ww0 + lane;
  const int wp = (ww >= 2) ? ww - 2 : ww + 98;
  const bool wok = hok && (ww < 100) && (wp < 96);
  const float* xb = x + ((size_t)n * 512) * 9216 + (size_t)hp * 96 + wp;
#pragma unroll
  for (int i = 0; i < 16; ++i) {
    int c = grp + i * 4;
    tile[c][lane] = wok ? xb[(size_t)(c0 + c) * 9216] : 0.f;
  }
  __syncthreads();
#pragma unroll
  for (int i = 0; i < 16; ++i) {
    int wl = grp + i * 4;
    int www = ww0 + wl;
    if (www < 100) {
      int m = g * 10000 + hh * 100 + www;
      xbf[(size_t)m * 512 + c0 + lane] = f2bf(tile[lane][wl]);
    }
  }
}

// ---------------------------------------------------------------------------
// 8-phase 256x256 GEMM, BK=64, K=512 fixed, 512 thr (8 waves 2Mx4N).
// D[row,col] = sum_k A[row,k]*B[col,k]; both row-major, stride 512.
// LDS 128KB double-buffered, XOR-swizzled (byte ^= (row&7)<<4) via
// pre-swizzled global source + swizzled ds_read.
// EPI 0: qkv epilogue (bf16 scalar, +bias[col]).
// EPI 1: out scatter: LDS-assembled per-channel ww-contiguous float4 runs.
// ---------------------------------------------------------------------------
template <int EPI, int NB, int MODE>
__global__ __launch_bounds__(512, 2) void gemm8(
    const uint16_t* __restrict__ A, const uint16_t* __restrict__ B,
    const float* __restrict__ bias, uint16_t* __restrict__ Cbf,
    float* __restrict__ Cout, int Mg, int n0) {
  __shared__ alignas(16) uint16_t lds[65536];  // 128 KB
  const int t = threadIdx.x;
  const int w = t >> 6, lane = t & 63;
  const int wr = w >> 2, wc = w & 3;
  const int lr = lane & 15, lg = lane >> 4;

  // bijective XCD swizzle (m204)
  const int nwg = gridDim.x, bid = blockIdx.x;
  const int q = nwg >> 3, r = nwg & 7;
  const int xc = bid & 7, li = bid >> 3;
  const int wg = (xc < r ? xc * (q + 1) : r * (q + 1) + (xc - r) * q) + li;
  int bm, bn;
  if (MODE == 0) { bm = wg / NB; bn = wg % NB; }
  else           { bm = wg % NB; bn = wg / NB; }

  // stage one half-tile: h 0=A-lo 1=A-hi 2=B-lo 3=B-hi (16KB, 2 loads/thr)
  auto STAGE = [&](int kt, int h) {
    const uint16_t* src = (h < 2) ? A : B;
    const int row0 = ((h < 2) ? bm * 256 : bn * 256) + (h & 1) * 128;
    const int base = ((h < 2) ? 0 : 32768) + (kt & 1) * 16384 + (h & 1) * 8192;
#pragma unroll
    for (int i = 0; i < 2; ++i) {
      int e = i * 512 + t;
      int row = e >> 3, slot = e & 7;
      const uint16_t* g = src + (size_t)(row0 + row) * 512 + kt * 64 +
                          ((slot ^ (row & 7)) << 3);
      g2lds16(g, &lds[base + ((i * 512 + w * 64) << 3)]);
    }
  };
  auto LDA = [&](int cur, int mi, int k2) -> bf16x8 {
    int row = wr * 128 + mi * 16 + lr;
    int byte = cur * 32768 + row * 128 + (((k2 * 32 + lg * 8) * 2) ^ ((row & 7) << 4));
    return *(const bf16x8*)((const char*)lds + byte);
  };
  auto LDB = [&](int cur, int ni, int k2) -> bf16x8 {
    int row = wc * 64 + ni * 16 + lr;
    int byte = 65536 + cur * 32768 + row * 128 +
               (((k2 * 32 + lg * 8) * 2) ^ ((row & 7) << 4));
    return *(const bf16x8*)((const char*)lds + byte);
  };

  f32x4 acc[8][4];
#pragma unroll
  for (int mi = 0; mi < 8; ++mi)
#pragma unroll
    for (int ni = 0; ni < 4; ++ni) acc[mi][ni] = (f32x4){0.f, 0.f, 0.f, 0.f};

  // prologue: K0 all 4 halves + K1 A-halves; vmcnt(4) -> K0 landed
  STAGE(0, 0); STAGE(0, 1); STAGE(0, 2); STAGE(0, 3);
  STAGE(1, 0); STAGE(1, 1);
  asm volatile("s_waitcnt vmcnt(4)" ::: "memory");
  BAR;

#define MFMAQ(AF, BF, MIOFF, NIOFF)                                        \
  __builtin_amdgcn_s_setprio(1);                                           \
  _Pragma("unroll") for (int mi = 0; mi < 4; ++mi)                         \
  _Pragma("unroll") for (int ni = 0; ni < 2; ++ni)                         \
  _Pragma("unroll") for (int k2 = 0; k2 < 2; ++k2)                         \
      acc[mi + MIOFF][ni + NIOFF] = __builtin_amdgcn_mfma_f32_16x16x32_bf16( \
          AF[mi][k2], BF[ni][k2], acc[mi + MIOFF][ni + NIOFF], 0, 0, 0);   \
  __builtin_amdgcn_s_setprio(0);

  for (int j = 0; j < 8; ++j) {
    const int cur = j & 1;
    bf16x8 a0[4][2], a1[4][2], b0[2][2], b1[2][2];
    // ---- phase 0: load lo frags, stage (j+1, B-lo)
#pragma unroll
    for (int mi = 0; mi < 4; ++mi)
#pragma unroll
      for (int k2 = 0; k2 < 2; ++k2) a0[mi][k2] = LDA(cur, mi, k2);
#pragma unroll
    for (int ni = 0; ni < 2; ++ni)
#pragma unroll
      for (int k2 = 0; k2 < 2; ++k2) b0[ni][k2] = LDB(cur, ni, k2);
    if (j + 1 < 8) STAGE(j + 1, 2);
    BAR;
    SCHED0;
    MFMAQ(a0, b0, 0, 0);
    BAR;
    // ---- phase 1: load hi frags, stage (j+1, B-hi)
#pragma unroll
    for (int mi = 0; mi < 4; ++mi)
#pragma unroll
      for (int k2 = 0; k2 < 2; ++k2) a1[mi][k2] = LDA(cur, mi + 4, k2);
#pragma unroll
    for (int ni = 0; ni < 2; ++ni)
#pragma unroll
      for (int k2 = 0; k2 < 2; ++k2) b1[ni][k2] = LDB(cur, ni + 2, k2);
    if (j + 1 < 8) STAGE(j + 1, 3);
    BAR;
    SCHED0;
    MFMAQ(a1, b1, 4, 2);
    BAR;
    // ---- phase 2: stage (j+2, A-lo)
    if (j + 2 < 8) STAGE(j + 2, 0);
    BAR;
    SCHED0;
    MFMAQ(a0, b1, 0, 2);
    BAR;
    // ---- phase 3: stage (j+2, A-hi), counted vmcnt
    if (j + 2 < 8) STAGE(j + 2, 1);
    if (j < 6) { asm volatile("s_waitcnt vmcnt(4)" ::: "memory"); }
    else       { asm volatile("s_waitcnt vmcnt(0)" ::: "memory"); }
    BAR;
    SCHED0;
    MFMAQ(a1, b0, 4, 0);
    BAR;
  }
#undef MFMAQ

  if (EPI == 0) {
#pragma unroll
    for (int ni = 0; ni < 4; ++ni) {
      int col = bn * 256 + wc * 64 + ni * 16 + lr;
      float bb = bias[col];
#pragma unroll
      for (int mi = 0; mi < 8; ++mi) {
        int row = bm * 256 + wr * 128 + mi * 16 + lg * 4;
#pragma unroll
        for (int rr = 0; rr < 4; ++rr)
          Cbf[(size_t)(row + rr) * 1536 + col] = f2bf(acc[mi][ni][rr] + bb);
      }
    }
  } else {
    // acc: c_local = wr*128 + mi*16 + lg*4 + rr ; tok = bn*256 + wc*64 + ni*16 + lr
    __syncthreads();
    float* ldsF = (float*)lds;  // [256][68] fp32
#pragma unroll
    for (int p = 0; p < 4; ++p) {
      if (wc == p) {
#pragma unroll
        for (int mi = 0; mi < 8; ++mi) {
          const float* b4 = &bias[bm * 256 + wr * 128 + mi * 16 + lg * 4];
#pragma unroll
          for (int ni = 0; ni < 4; ++ni)
#pragma unroll
            for (int rr = 0; rr < 4; ++rr)
              ldsF[(wr * 128 + mi * 16 + lg * 4 + rr) * 68 + ni * 16 + lr] =
                  acc[mi][ni][rr] + b4[rr];
        }
      }
      __syncthreads();
      // emit: 256 channels x 16 token-quads (64 tokens of pass p);
      // hh-major tokens => quad = 4 consecutive ww (ww % 4 == 0).
#pragma unroll
      for (int i = 0; i < 8; ++i) {
        int e = i * 512 + t;                  // 4096 chunks
        int q4 = e & 15, c = e >> 4;
        int tok = bn * 256 + p * 64 + q4 * 4;
        int g = tok / 10000, rem = tok - g * 10000;
        int hh = rem / 100, ww = rem - hh * 100;
        if (hh >= 2 && hh < 98) {
          float4 v = *(const float4*)&ldsF[c * 68 + q4 * 4];
          size_t base = ((size_t)(n0 + g) * 512 + bm * 256 + c) * 9216 +
                        (size_t)(hh - 2) * 96;
          if (ww >= 4 && ww <= 92) {
            *(float4*)&Cout[base + ww - 2] = v;          // full quad
          } else if (ww == 0) {
            Cout[base + 0] = v.z; Cout[base + 1] = v.w;  // ww=2,3
          } else if (ww == 96) {
            Cout[base + 94] = v.x; Cout[base + 95] = v.y; // ww=96,97
          }
        }
      }
      __syncthreads();
    }
  }
}

// ---------------------------------------------------------------------------
// Attention: 1 block/window, 128 thr = (head h, query qi). K/V staged in LDS,
// Q read direct. fp32 VALU softmax.
// ---------------------------------------------------------------------------
__global__ __launch_bounds__(128) void attn_kernel(
    const uint16_t* __restrict__ qkv, const float* __restrict__ x,
    uint16_t* __restrict__ obuf, int n0) {
  __shared__ alignas(16) uint16_t skv[16][1024];  // [row][K(512) V(512)]
  __shared__ float smask[16];
  const int b = blockIdx.x;
  const int g = b / 625, wid = b % 625;
  const int ib = wid / 25, jb = wid % 25;
  const int t = threadIdx.x;
  const int wv = t >> 6;
  const int h = t >> 4, qi = t & 15;

  const int mbase = g * 10000 + ib * 400 + jb * 4;  // hh-major token rows

#pragma unroll
  for (int it = 0; it < 16; ++it) {
    int e = it * 128 + t;                 // 16B chunk id in [0,2048)
    int l = e >> 7, c = e & 127;
    int m = mbase + (l >> 2) * 100 + (l & 3);
    const uint16_t* src = qkv + (size_t)m * 1536 + 512 + c * 8;
    g2lds16(src, (uint16_t*)skv + (it * 128 + wv * 64) * 8);
  }
  const int mq = mbase + (qi >> 2) * 100 + (qi & 3);
  float qv[64];
#pragma unroll
  for (int d8 = 0; d8 < 8; ++d8) {
    u16x8 v = *(const u16x8*)&qkv[(size_t)mq * 1536 + h * 64 + d8 * 8];
#pragma unroll
    for (int j = 0; j < 8; ++j) qv[d8 * 8 + j] = bf2f(v[j]);
  }
  if (t < 16) {
    int hh = ib * 4 + (t >> 2), ww = jb * 4 + (t & 3);
    int a = (hh >= 4) ? hh - 4 : hh + 96;
    int c = (ww >= 4) ? ww - 4 : ww + 96;
    smask[t] = (a < 96 && c < 96)
                   ? x[((size_t)(n0 + g) * 512) * 9216 + (size_t)a * 96 + c]
                   : 0.f;
  }
  __syncthreads();

  float s[16];
  float mx = -1e30f;
#pragma unroll
  for (int ki = 0; ki < 16; ++ki) {
    float a = 0.f;
#pragma unroll
    for (int d8 = 0; d8 < 8; ++d8) {
      u16x8 kv = *(const u16x8*)&skv[ki][h * 64 + d8 * 8];
#pragma unroll
      for (int j = 0; j < 8; ++j) a += qv[d8 * 8 + j] * bf2f(kv[j]);
    }
    s[ki] = a * 0.125f + smask[ki];
    mx = fmaxf(mx, s[ki]);
  }
  float sum = 0.f;
#pragma unroll
  for (int ki = 0; ki < 16; ++ki) { s[ki] = __expf(s[ki] - mx); sum += s[ki]; }
  const float inv = 1.f / sum;
  float o[64];
#pragma unroll
  for (int d = 0; d < 64; ++d) o[d] = 0.f;
#pragma unroll
  for (int ki = 0; ki < 16; ++ki) {
    float wgt = s[ki] * inv;
#pragma unroll
    for (int d8 = 0; d8 < 8; ++d8) {
      u16x8 vv = *(const u16x8*)&skv[ki][512 + h * 64 + d8 * 8];
#pragma unroll
      for (int j = 0; j < 8; ++j) o[d8 * 8 + j] += wgt * bf2f(vv[j]);
    }
  }
#pragma unroll
  for (int d8 = 0; d8 < 8; ++d8) {
    alignas(16) uint16_t tmp[8];
#pragma unroll
    for (int j = 0; j < 8; ++j) tmp[j] = f2bf(o[d8 * 8 + j]);
    *(uint4*)&obuf[(size_t)mq * 512 + h * 64 + d8 * 8] = *(uint4*)tmp;
  }
}

// ---------------------------------------------------------------------------
extern "C" void kernel_launch(void* const* d_in, const int* in_sizes, int n_in,
                              void* d_out, int out_size, void* d_ws, size_t ws_size,
                              hipStream_t stream) {
  const float* x  = (const float*)d_in[0];
  const float* wq = (const float*)d_in[1];
  const float* bq = (const float*)d_in[2];
  const float* wo = (const float*)d_in[3];
  const float* bo = (const float*)d_in[4];
  float* out = (float*)d_out;
  uint8_t* ws = (uint8_t*)d_ws;

  uint16_t* wq_bf = (uint16_t*)ws;               // 1.5 MB
  uint16_t* wo_bf = (uint16_t*)(ws + 1572864);   // 0.5 MB
  uint8_t* bufbase = ws + 2097152;

  int G = 16;
  while (G > 1) {
    int Mg = G * 10000;
    int Mp = ((Mg + 255) / 256) * 256;
    size_t need = (size_t)2097152 + (size_t)Mp * 4096;
    if (need <= ws_size) break;
    G >>= 1;
  }
  const int Mg = G * 10000;
  const int Mp = ((Mg + 255) / 256) * 256;
  uint16_t* xo   = (uint16_t*)bufbase;                        // Mp*512 (X, then O)
  uint16_t* qkvb = (uint16_t*)(bufbase + (size_t)Mp * 1024);  // Mp*1536

  cvt_weights<<<dim3(3072), dim3(256), 0, stream>>>(wq, wo, wq_bf, wo_bf);

  for (int n0 = 0; n0 < 16; n0 += G) {
    gather_kernel<<<dim3(2, 8, G * 100), dim3(256), 0, stream>>>(x, xo, n0);
    // qkv[m,1536] = X @ Wqkv^T + b
    gemm8<0, 6, 0><<<dim3((Mp / 256) * 6), dim3(512), 0, stream>>>(
        xo, wq_bf, bq, qkvb, nullptr, Mg, n0);
    attn_kernel<<<dim3(G * 625), dim3(128), 0, stream>>>(qkvb, x, xo, n0);
    // out[c,tok] = Wout @ O^T + b, scattered to (N,C,96,96)
    gemm8<1, 2, 1><<<dim3((Mp / 256) * 2), dim3(512), 0, stream>>>(
        wo_bf, xo, bo, nullptr, out, Mg, n0);
  }
  (void)in_sizes; (void)n_in; (void)out_size;
}

// Round 17
// 969.993 us; speedup vs baseline: 3.4132x; 1.0036x over previous
//
#include <hip/hip_runtime.h>
#include <cstdint>

// ---------------------------------------------------------------------------
// WindowAttention: pad 96->100, roll(+2,+2), 4x4 windows, MHA(8 heads,d=64),
// un-window, roll back, crop. Token m = g*10000 + hh*100 + ww (hh-major).
// Pipeline: gather -> qkv GEMM (256^2 8-phase) -> window attn -> out GEMM.
// R9 base (973us, reproduced) + packed-pair attn VALU (isolated this round).
// ---------------------------------------------------------------------------

typedef __attribute__((ext_vector_type(8))) __bf16 bf16x8;
typedef __attribute__((ext_vector_type(8))) uint16_t u16x8;
typedef __attribute__((ext_vector_type(4))) float f32x4;
typedef __attribute__((ext_vector_type(2))) float f32x2;
typedef __attribute__((ext_vector_type(4))) uint32_t u32x4;

__device__ __forceinline__ uint16_t f2bf(float f) {
  union { float f; uint32_t u; } c; c.f = f;
  uint32_t r = c.u + 0x7FFFu + ((c.u >> 16) & 1u);  // RNE
  return (uint16_t)(r >> 16);
}
__device__ __forceinline__ float bf2f(uint16_t u) {
  union { uint32_t u; float f; } c; c.u = ((uint32_t)u) << 16;
  return c.f;
}
__device__ __forceinline__ f32x2 bf2x2(uint32_t u) {  // (lo bf16, hi bf16) -> f32x2
  union { uint32_t u; float f; } lo, hi;
  lo.u = u << 16;
  hi.u = u & 0xffff0000u;
  f32x2 r; r.x = lo.f; r.y = hi.f; return r;
}

__device__ __forceinline__ void g2lds16(const void* g, void* lds) {
  __builtin_amdgcn_global_load_lds(
      (const __attribute__((address_space(1))) uint32_t*)(uintptr_t)g,
      (__attribute__((address_space(3))) uint32_t*)(uintptr_t)lds,
      16, 0, 0);
}

#define CFENCE asm volatile("" ::: "memory")
#define BAR do { CFENCE; __builtin_amdgcn_s_barrier(); CFENCE; } while (0)
#define SCHED0 __builtin_amdgcn_sched_barrier(0)

// ---------------------------------------------------------------------------
__global__ void cvt_weights(const float* __restrict__ w1, const float* __restrict__ w2,
                            uint16_t* __restrict__ o1, uint16_t* __restrict__ o2) {
  int i = blockIdx.x * 256 + threadIdx.x;
  if (i < 786432) o1[i] = f2bf(w1[i]);
  if (i < 262144) o2[i] = f2bf(w2[i]);
}

// ---------------------------------------------------------------------------
// Gather: x (NCHW fp32) -> token-major bf16 X[m,512]; pad+roll folded in.
// ---------------------------------------------------------------------------
__global__ __launch_bounds__(256) void gather_kernel(
    const float* __restrict__ x, uint16_t* __restrict__ xbf, int n0) {
  __shared__ float tile[64][65];
  const int z = blockIdx.z;
  const int g = z / 100, hh = z % 100;
  const int c0 = blockIdx.y * 64, ww0 = blockIdx.x * 64;
  const int n = n0 + g;
  const int hp = (hh >= 2) ? hh - 2 : hh + 98;
  const bool hok = hp < 96;
  const int t = threadIdx.x;
  const int lane = t & 63, grp = t >> 6;

  const int ww = ww0 + lane;
  const int wp = (ww >= 2) ? ww - 2 : ww + 98;
  const bool wok = hok && (ww < 100) && (wp < 96);
  const float* xb = x + ((size_t)n * 512) * 9216 + (size_t)hp * 96 + wp;
#pragma unroll
  for (int i = 0; i < 16; ++i) {
    int c = grp + i * 4;
    tile[c][lane] = wok ? xb[(size_t)(c0 + c) * 9216] : 0.f;
  }
  __syncthreads();
#pragma unroll
  for (int i = 0; i < 16; ++i) {
    int wl = grp + i * 4;
    int www = ww0 + wl;
    if (www < 100) {
      int m = g * 10000 + hh * 100 + www;
      xbf[(size_t)m * 512 + c0 + lane] = f2bf(tile[lane][wl]);
    }
  }
}

// ---------------------------------------------------------------------------
// 8-phase 256x256 GEMM, BK=64, K=512 fixed, 512 thr (8 waves 2Mx4N).
// D[row,col] = sum_k A[row,k]*B[col,k]; both row-major, stride 512.
// LDS 128KB double-buffered, XOR-swizzled (byte ^= (row&7)<<4) via
// pre-swizzled global source + swizzled ds_read.
// EPI 0: qkv epilogue (bf16 scalar, +bias[col]).
// EPI 1: out scatter: LDS-assembled per-channel ww-contiguous float4 runs.
// ---------------------------------------------------------------------------
template <int EPI, int NB, int MODE>
__global__ __launch_bounds__(512, 2) void gemm8(
    const uint16_t* __restrict__ A, const uint16_t* __restrict__ B,
    const float* __restrict__ bias, uint16_t* __restrict__ Cbf,
    float* __restrict__ Cout, int Mg, int n0) {
  __shared__ alignas(16) uint16_t lds[65536];  // 128 KB
  const int t = threadIdx.x;
  const int w = t >> 6, lane = t & 63;
  const int wr = w >> 2, wc = w & 3;
  const int lr = lane & 15, lg = lane >> 4;

  // bijective XCD swizzle (m204)
  const int nwg = gridDim.x, bid = blockIdx.x;
  const int q = nwg >> 3, r = nwg & 7;
  const int xc = bid & 7, li = bid >> 3;
  const int wg = (xc < r ? xc * (q + 1) : r * (q + 1) + (xc - r) * q) + li;
  int bm, bn;
  if (MODE == 0) { bm = wg / NB; bn = wg % NB; }
  else           { bm = wg % NB; bn = wg / NB; }

  // stage one half-tile: h 0=A-lo 1=A-hi 2=B-lo 3=B-hi (16KB, 2 loads/thr)
  auto STAGE = [&](int kt, int h) {
    const uint16_t* src = (h < 2) ? A : B;
    const int row0 = ((h < 2) ? bm * 256 : bn * 256) + (h & 1) * 128;
    const int base = ((h < 2) ? 0 : 32768) + (kt & 1) * 16384 + (h & 1) * 8192;
#pragma unroll
    for (int i = 0; i < 2; ++i) {
      int e = i * 512 + t;
      int row = e >> 3, slot = e & 7;
      const uint16_t* g = src + (size_t)(row0 + row) * 512 + kt * 64 +
                          ((slot ^ (row & 7)) << 3);
      g2lds16(g, &lds[base + ((i * 512 + w * 64) << 3)]);
    }
  };
  auto LDA = [&](int cur, int mi, int k2) -> bf16x8 {
    int row = wr * 128 + mi * 16 + lr;
    int byte = cur * 32768 + row * 128 + (((k2 * 32 + lg * 8) * 2) ^ ((row & 7) << 4));
    return *(const bf16x8*)((const char*)lds + byte);
  };
  auto LDB = [&](int cur, int ni, int k2) -> bf16x8 {
    int row = wc * 64 + ni * 16 + lr;
    int byte = 65536 + cur * 32768 + row * 128 +
               (((k2 * 32 + lg * 8) * 2) ^ ((row & 7) << 4));
    return *(const bf16x8*)((const char*)lds + byte);
  };

  f32x4 acc[8][4];
#pragma unroll
  for (int mi = 0; mi < 8; ++mi)
#pragma unroll
    for (int ni = 0; ni < 4; ++ni) acc[mi][ni] = (f32x4){0.f, 0.f, 0.f, 0.f};

  // prologue: K0 all 4 halves + K1 A-halves; vmcnt(4) -> K0 landed
  STAGE(0, 0); STAGE(0, 1); STAGE(0, 2); STAGE(0, 3);
  STAGE(1, 0); STAGE(1, 1);
  asm volatile("s_waitcnt vmcnt(4)" ::: "memory");
  BAR;

#define MFMAQ(AF, BF, MIOFF, NIOFF)                                        \
  __builtin_amdgcn_s_setprio(1);                                           \
  _Pragma("unroll") for (int mi = 0; mi < 4; ++mi)                         \
  _Pragma("unroll") for (int ni = 0; ni < 2; ++ni)                         \
  _Pragma("unroll") for (int k2 = 0; k2 < 2; ++k2)                         \
      acc[mi + MIOFF][ni + NIOFF] = __builtin_amdgcn_mfma_f32_16x16x32_bf16( \
          AF[mi][k2], BF[ni][k2], acc[mi + MIOFF][ni + NIOFF], 0, 0, 0);   \
  __builtin_amdgcn_s_setprio(0);

  for (int j = 0; j < 8; ++j) {
    const int cur = j & 1;
    bf16x8 a0[4][2], a1[4][2], b0[2][2], b1[2][2];
    // ---- phase 0: load lo frags, stage (j+1, B-lo)
#pragma unroll
    for (int mi = 0; mi < 4; ++mi)
#pragma unroll
      for (int k2 = 0; k2 < 2; ++k2) a0[mi][k2] = LDA(cur, mi, k2);
#pragma unroll
    for (int ni = 0; ni < 2; ++ni)
#pragma unroll
      for (int k2 = 0; k2 < 2; ++k2) b0[ni][k2] = LDB(cur, ni, k2);
    if (j + 1 < 8) STAGE(j + 1, 2);
    BAR;
    SCHED0;
    MFMAQ(a0, b0, 0, 0);
    BAR;
    // ---- phase 1: load hi frags, stage (j+1, B-hi)
#pragma unroll
    for (int mi = 0; mi < 4; ++mi)
#pragma unroll
      for (int k2 = 0; k2 < 2; ++k2) a1[mi][k2] = LDA(cur, mi + 4, k2);
#pragma unroll
    for (int ni = 0; ni < 2; ++ni)
#pragma unroll
      for (int k2 = 0; k2 < 2; ++k2) b1[ni][k2] = LDB(cur, ni + 2, k2);
    if (j + 1 < 8) STAGE(j + 1, 3);
    BAR;
    SCHED0;
    MFMAQ(a1, b1, 4, 2);
    BAR;
    // ---- phase 2: stage (j+2, A-lo)
    if (j + 2 < 8) STAGE(j + 2, 0);
    BAR;
    SCHED0;
    MFMAQ(a0, b1, 0, 2);
    BAR;
    // ---- phase 3: stage (j+2, A-hi), counted vmcnt
    if (j + 2 < 8) STAGE(j + 2, 1);
    if (j < 6) { asm volatile("s_waitcnt vmcnt(4)" ::: "memory"); }
    else       { asm volatile("s_waitcnt vmcnt(0)" ::: "memory"); }
    BAR;
    SCHED0;
    MFMAQ(a1, b0, 4, 0);
    BAR;
  }
#undef MFMAQ

  if (EPI == 0) {
#pragma unroll
    for (int ni = 0; ni < 4; ++ni) {
      int col = bn * 256 + wc * 64 + ni * 16 + lr;
      float bb = bias[col];
#pragma unroll
      for (int mi = 0; mi < 8; ++mi) {
        int row = bm * 256 + wr * 128 + mi * 16 + lg * 4;
#pragma unroll
        for (int rr = 0; rr < 4; ++rr)
          Cbf[(size_t)(row + rr) * 1536 + col] = f2bf(acc[mi][ni][rr] + bb);
      }
    }
  } else {
    // acc: c_local = wr*128 + mi*16 + lg*4 + rr ; tok = bn*256 + wc*64 + ni*16 + lr
    __syncthreads();
    float* ldsF = (float*)lds;  // [256][68] fp32
#pragma unroll
    for (int p = 0; p < 4; ++p) {
      if (wc == p) {
#pragma unroll
        for (int mi = 0; mi < 8; ++mi) {
          const float* b4 = &bias[bm * 256 + wr * 128 + mi * 16 + lg * 4];
#pragma unroll
          for (int ni = 0; ni < 4; ++ni)
#pragma unroll
            for (int rr = 0; rr < 4; ++rr)
              ldsF[(wr * 128 + mi * 16 + lg * 4 + rr) * 68 + ni * 16 + lr] =
                  acc[mi][ni][rr] + b4[rr];
        }
      }
      __syncthreads();
      // emit: 256 channels x 16 token-quads (64 tokens of pass p);
      // hh-major tokens => quad = 4 consecutive ww (ww % 4 == 0).
#pragma unroll
      for (int i = 0; i < 8; ++i) {
        int e = i * 512 + t;                  // 4096 chunks
        int q4 = e & 15, c = e >> 4;
        int tok = bn * 256 + p * 64 + q4 * 4;
        int g = tok / 10000, rem = tok - g * 10000;
        int hh = rem / 100, ww = rem - hh * 100;
        if (hh >= 2 && hh < 98) {
          float4 v = *(const float4*)&ldsF[c * 68 + q4 * 4];
          size_t base = ((size_t)(n0 + g) * 512 + bm * 256 + c) * 9216 +
                        (size_t)(hh - 2) * 96;
          if (ww >= 4 && ww <= 92) {
            *(float4*)&Cout[base + ww - 2] = v;          // full quad
          } else if (ww == 0) {
            Cout[base + 0] = v.z; Cout[base + 1] = v.w;  // ww=2,3
          } else if (ww == 96) {
            Cout[base + 94] = v.x; Cout[base + 95] = v.y; // ww=96,97
          }
        }
      }
      __syncthreads();
    }
  }
}

// ---------------------------------------------------------------------------
// Attention: 1 block/window, 128 thr = (head h, query qi). K/V staged in LDS,
// Q read direct. fp32 softmax with packed-pair (f32x2 -> v_pk_fma) math.
// ---------------------------------------------------------------------------
__global__ __launch_bounds__(128) void attn_kernel(
    const uint16_t* __restrict__ qkv, const float* __restrict__ x,
    uint16_t* __restrict__ obuf, int n0) {
  __shared__ alignas(16) uint16_t skv[16][1024];  // [row][K(512) V(512)]
  __shared__ float smask[16];
  const int b = blockIdx.x;
  const int g = b / 625, wid = b % 625;
  const int ib = wid / 25, jb = wid % 25;
  const int t = threadIdx.x;
  const int wv = t >> 6;
  const int h = t >> 4, qi = t & 15;

  const int mbase = g * 10000 + ib * 400 + jb * 4;  // hh-major token rows

#pragma unroll
  for (int it = 0; it < 16; ++it) {
    int e = it * 128 + t;                 // 16B chunk id in [0,2048)
    int l = e >> 7, c = e & 127;
    int m = mbase + (l >> 2) * 100 + (l & 3);
    const uint16_t* src = qkv + (size_t)m * 1536 + 512 + c * 8;
    g2lds16(src, (uint16_t*)skv + (it * 128 + wv * 64) * 8);
  }
  const int mq = mbase + (qi >> 2) * 100 + (qi & 3);
  f32x2 qv2[32];
#pragma unroll
  for (int d4 = 0; d4 < 8; ++d4) {
    u32x4 qw = *(const u32x4*)&qkv[(size_t)mq * 1536 + h * 64 + d4 * 8];
#pragma unroll
    for (int j = 0; j < 4; ++j) qv2[d4 * 4 + j] = bf2x2(qw[j]);
  }
  if (t < 16) {
    int hh = ib * 4 + (t >> 2), ww = jb * 4 + (t & 3);
    int a = (hh >= 4) ? hh - 4 : hh + 96;
    int c = (ww >= 4) ? ww - 4 : ww + 96;
    smask[t] = (a < 96 && c < 96)
                   ? x[((size_t)(n0 + g) * 512) * 9216 + (size_t)a * 96 + c]
                   : 0.f;
  }
  __syncthreads();

  float s[16];
  float mx = -1e30f;
#pragma unroll
  for (int ki = 0; ki < 16; ++ki) {
    f32x2 a2; a2.x = 0.f; a2.y = 0.f;
#pragma unroll
    for (int d4 = 0; d4 < 8; ++d4) {
      u32x4 kw = *(const u32x4*)&skv[ki][h * 64 + d4 * 8];
#pragma unroll
      for (int j = 0; j < 4; ++j) a2 += bf2x2(kw[j]) * qv2[d4 * 4 + j];
    }
    s[ki] = (a2.x + a2.y) * 0.125f + smask[ki];
    mx = fmaxf(mx, s[ki]);
  }
  float sum = 0.f;
#pragma unroll
  for (int ki = 0; ki < 16; ++ki) { s[ki] = __expf(s[ki] - mx); sum += s[ki]; }
  const float inv = 1.f / sum;
  f32x2 o2[32];
#pragma unroll
  for (int d = 0; d < 32; ++d) { o2[d].x = 0.f; o2[d].y = 0.f; }
#pragma unroll
  for (int ki = 0; ki < 16; ++ki) {
    float wgt = s[ki] * inv;
    f32x2 w2; w2.x = wgt; w2.y = wgt;
#pragma unroll
    for (int d4 = 0; d4 < 8; ++d4) {
      u32x4 vw = *(const u32x4*)&skv[ki][512 + h * 64 + d4 * 8];
#pragma unroll
      for (int j = 0; j < 4; ++j) o2[d4 * 4 + j] += bf2x2(vw[j]) * w2;
    }
  }
#pragma unroll
  for (int d4 = 0; d4 < 8; ++d4) {
    alignas(16) uint16_t tmp[8];
#pragma unroll
    for (int j = 0; j < 4; ++j) {
      tmp[2 * j]     = f2bf(o2[d4 * 4 + j].x);
      tmp[2 * j + 1] = f2bf(o2[d4 * 4 + j].y);
    }
    *(uint4*)&obuf[(size_t)mq * 512 + h * 64 + d4 * 8] = *(uint4*)tmp;
  }
}

// ---------------------------------------------------------------------------
extern "C" void kernel_launch(void* const* d_in, const int* in_sizes, int n_in,
                              void* d_out, int out_size, void* d_ws, size_t ws_size,
                              hipStream_t stream) {
  const float* x  = (const float*)d_in[0];
  const float* wq = (const float*)d_in[1];
  const float* bq = (const float*)d_in[2];
  const float* wo = (const float*)d_in[3];
  const float* bo = (const float*)d_in[4];
  float* out = (float*)d_out;
  uint8_t* ws = (uint8_t*)d_ws;

  uint16_t* wq_bf = (uint16_t*)ws;               // 1.5 MB
  uint16_t* wo_bf = (uint16_t*)(ws + 1572864);   // 0.5 MB
  uint8_t* bufbase = ws + 2097152;

  int G = 16;
  while (G > 1) {
    int Mg = G * 10000;
    int Mp = ((Mg + 255) / 256) * 256;
    size_t need = (size_t)2097152 + (size_t)Mp * 4096;
    if (need <= ws_size) break;
    G >>= 1;
  }
  const int Mg = G * 10000;
  const int Mp = ((Mg + 255) / 256) * 256;
  uint16_t* xo   = (uint16_t*)bufbase;                        // Mp*512 (X, then O)
  uint16_t* qkvb = (uint16_t*)(bufbase + (size_t)Mp * 1024);  // Mp*1536

  cvt_weights<<<dim3(3072), dim3(256), 0, stream>>>(wq, wo, wq_bf, wo_bf);

  for (int n0 = 0; n0 < 16; n0 += G) {
    gather_kernel<<<dim3(2, 8, G * 100), dim3(256), 0, stream>>>(x, xo, n0);
    // qkv[m,1536] = X @ Wqkv^T + b
    gemm8<0, 6, 0><<<dim3((Mp / 256) * 6), dim3(512), 0, stream>>>(
        xo, wq_bf, bq, qkvb, nullptr, Mg, n0);
    attn_kernel<<<dim3(G * 625), dim3(128), 0, stream>>>(qkvb, x, xo, n0);
    // out[c,tok] = Wout @ O^T + b, scattered to (N,C,96,96)
    gemm8<1, 2, 1><<<dim3((Mp / 256) * 2), dim3(512), 0, stream>>>(
        wo_bf, xo, bo, nullptr, out, Mg, n0);
  }
  (void)in_sizes; (void)n_in; (void)out_size;
}